// Round 2
// baseline (350.109 us; speedup 1.0000x reference)
//
#include <hip/hip_runtime.h>

#define NBINS 512
#define BDIM 256

// ---------------------------------------------------------------------------
// Kernel 1: gather + rowmax. One block per batch row b. Wave w (0..3) keeps the
// base row outputs[b,:] in registers (8 floats/lane) and processes 4 neighbors
// k = w*4..w*4+3, giving 8 independent float4 gather loads in flight per wave.
// No LDS, no barriers. Results add[b*K + k] written by lane 0 as one float4.
// ---------------------------------------------------------------------------
__global__ __launch_bounds__(BDIM) void gather_kernel(
        const float* __restrict__ outputs,
        const float* __restrict__ y,
        float* __restrict__ add,        // (B*K) in ws
        int K) {
    const int b    = blockIdx.x;
    const int w    = threadIdx.x >> 6;
    const int lane = threadIdx.x & 63;

    const float4* bp = (const float4*)(outputs + (size_t)b * NBINS);
    const float4  b0 = bp[lane * 2];
    const float4  b1 = bp[lane * 2 + 1];

    const int kbase = w * 4;
    int nn[4];
    #pragma unroll
    for (int j = 0; j < 4; ++j)
        nn[j] = (int)y[b * K + kbase + j];   // y >= 0 so trunc == int cast

    float4 g0[4], g1[4];
    #pragma unroll
    for (int j = 0; j < 4; ++j) {
        const float4* gp = (const float4*)(outputs + (size_t)nn[j] * NBINS);
        g0[j] = gp[lane * 2];
        g1[j] = gp[lane * 2 + 1];
    }

    float m[4];
    #pragma unroll
    for (int j = 0; j < 4; ++j) {
        m[j] = fmaxf(fmaxf(fmaxf(g0[j].x + b0.x, g0[j].y + b0.y),
                           fmaxf(g0[j].z + b0.z, g0[j].w + b0.w)),
                     fmaxf(fmaxf(g1[j].x + b1.x, g1[j].y + b1.y),
                           fmaxf(g1[j].z + b1.z, g1[j].w + b1.w)));
    }

    #pragma unroll
    for (int off = 32; off > 0; off >>= 1) {
        #pragma unroll
        for (int j = 0; j < 4; ++j)
            m[j] = fmaxf(m[j], __shfl_down(m[j], off, 64));
    }

    if (lane == 0) {
        float4 v = make_float4(m[0], m[1], m[2], m[3]);
        *((float4*)(add + (size_t)b * K + kbase)) = v;   // 16B-aligned (kbase%4==0)
    }
}

// ---------------------------------------------------------------------------
// Kernel 2: per-column partial sums, 256 blocks x 512 threads (thread = bin),
// each block sums a contiguous chunk of rows. Plain stores, no init needed.
// ---------------------------------------------------------------------------
__global__ __launch_bounds__(NBINS) void colsum_kernel(
        const float* __restrict__ outputs,
        float* __restrict__ part,       // (nblocks * NBINS) in ws
        int rows_per_block) {
    const int t = threadIdx.x;
    const size_t r0 = (size_t)blockIdx.x * rows_per_block;
    float local = 0.0f;
    for (int r = 0; r < rows_per_block; ++r)
        local += outputs[(r0 + r) * NBINS + t];
    part[(size_t)blockIdx.x * NBINS + t] = local;
}

// ---------------------------------------------------------------------------
// Kernel 3: booster weights + weighted-add block partials. 32 blocks x 256,
// one thread per batch element.
// ---------------------------------------------------------------------------
__global__ __launch_bounds__(BDIM) void booster_kernel(
        const float* __restrict__ add,
        const float* __restrict__ weights,
        float* __restrict__ out,        // [cost, diff, bnorm, booster(B)]
        float* __restrict__ wpartial,   // (gridDim.x) in ws
        int K) {
    __shared__ float sred[BDIM];
    const int t = threadIdx.x;
    const int b = blockIdx.x * BDIM + t;

    const float4* ap = (const float4*)(add + (size_t)b * K);
    float4 a0 = ap[0], a1 = ap[1], a2 = ap[2], a3 = ap[3];
    float sum = ((a0.x + a0.y) + (a0.z + a0.w))
              + ((a1.x + a1.y) + (a1.z + a1.w))
              + ((a2.x + a2.y) + (a2.z + a2.w))
              + ((a3.x + a3.y) + (a3.z + a3.w));

    float booster = fmaxf(0.5f, (2.0f - sum * (1.0f / 16.0f)) * 0.5f);
    out[3 + b] = booster;

    sred[t] = weights[b] * sum;
    __syncthreads();
    for (int s = BDIM / 2; s > 0; s >>= 1) {
        if (t < s) sred[t] += sred[t + s];
        __syncthreads();
    }
    if (t == 0) wpartial[blockIdx.x] = sred[0];
}

// ---------------------------------------------------------------------------
// Kernel 4: finalize. 512 threads: reduce column partials -> min/max; thread 0
// folds the weighted-add partials and writes the 3 scalars.
// ---------------------------------------------------------------------------
__global__ __launch_bounds__(NBINS) void final_kernel(
        const float* __restrict__ part,
        const float* __restrict__ wpartial,
        float* __restrict__ out,
        int npart, int nw, float inv_count, float inv_target) {
    __shared__ float smax[NBINS];
    __shared__ float smin[NBINS];
    const int t = threadIdx.x;
    float v = 0.0f;
    for (int j = 0; j < npart; ++j)
        v += part[(size_t)j * NBINS + t];
    smax[t] = v;
    smin[t] = v;
    __syncthreads();
    for (int s = NBINS / 2; s > 0; s >>= 1) {
        if (t < s) {
            smax[t] = fmaxf(smax[t], smax[t + s]);
            smin[t] = fminf(smin[t], smin[t + s]);
        }
        __syncthreads();
    }
    if (t == 0) {
        float acc = 0.0f;
        for (int i = 0; i < nw; ++i) acc += wpartial[i];
        float add_mean = acc * inv_count;
        float d = 2.0f - add_mean;
        float diff = d * d;
        float bn = (smax[0] - smin[0]) * inv_target;
        out[0] = bn + diff;
        out[1] = diff;
        out[2] = bn;
    }
}

extern "C" void kernel_launch(void* const* d_in, const int* in_sizes, int n_in,
                              void* d_out, int out_size, void* d_ws, size_t ws_size,
                              hipStream_t stream) {
    const float* outputs = (const float*)d_in[0];  // (N, 512)
    const float* y       = (const float*)d_in[1];  // (B, K)
    const float* weights = (const float*)d_in[2];  // (B,)
    float* out = (float*)d_out;

    const int B = in_sizes[2];              // 8192
    const int K = in_sizes[1] / B;          // 16
    const int N = in_sizes[0] / NBINS;      // 100000

    const int COL_BLOCKS = 256;
    const int rows_per_block = B / COL_BLOCKS;   // 32
    const int BOOST_BLOCKS = B / BDIM;           // 32

    // ws layout (floats): add[B*K] | colpart[COL_BLOCKS*NBINS] | wpartial[BOOST_BLOCKS]
    float* ws      = (float*)d_ws;
    float* add     = ws;
    float* colpart = add + (size_t)B * K;
    float* wpart   = colpart + (size_t)COL_BLOCKS * NBINS;

    gather_kernel<<<B, BDIM, 0, stream>>>(outputs, y, add, K);
    colsum_kernel<<<COL_BLOCKS, NBINS, 0, stream>>>(outputs, colpart, rows_per_block);
    booster_kernel<<<BOOST_BLOCKS, BDIM, 0, stream>>>(add, weights, out, wpart, K);
    final_kernel<<<1, NBINS, 0, stream>>>(colpart, wpart, out,
                                          COL_BLOCKS, BOOST_BLOCKS,
                                          1.0f / (float)(B * K),
                                          (float)NBINS / (float)N);
}

// Round 3
// 348.723 us; speedup vs baseline: 1.0040x; 1.0040x over previous
//
#include <hip/hip_runtime.h>

#define NBINS 512
#define BDIM 256

// ---------------------------------------------------------------------------
// Kernel 1: gather + rowmax + booster, fused. One block per batch row b.
// Wave w (0..3) holds base row outputs[b,:] in registers (8 floats/lane,
// loaded as two contiguous 1KB segments) and processes neighbors k=4w..4w+3
// (8 independent, fully-coalesced float4 gather loads in flight per wave).
// End: LDS reduce of the 16 add values -> booster -> out[3+b], and
// weights[b]*sum -> wpart[b] (plain store, no atomics).
// ---------------------------------------------------------------------------
__global__ __launch_bounds__(BDIM) void gather_kernel(
        const float* __restrict__ outputs,
        const float* __restrict__ y,
        const float* __restrict__ weights,
        float* __restrict__ out,        // [cost, diff, bnorm, booster(B)]
        float* __restrict__ wpart,      // (B) in ws
        int K) {
    __shared__ float s_add[16];

    const int b    = blockIdx.x;
    const int w    = threadIdx.x >> 6;
    const int lane = threadIdx.x & 63;

    // Base row: two contiguous 1KB segments (lane i -> float4 #i and #(64+i))
    const float4* bp = (const float4*)(outputs + (size_t)b * NBINS);
    const float4  b0 = bp[lane];
    const float4  b1 = bp[64 + lane];

    const int kbase = w * 4;
    int nn[4];
    #pragma unroll
    for (int j = 0; j < 4; ++j)
        nn[j] = (int)y[b * K + kbase + j];   // y >= 0 so trunc == int cast

    float4 g0[4], g1[4];
    #pragma unroll
    for (int j = 0; j < 4; ++j) {
        const float4* gp = (const float4*)(outputs + (size_t)nn[j] * NBINS);
        g0[j] = gp[lane];
        g1[j] = gp[64 + lane];
    }

    float m[4];
    #pragma unroll
    for (int j = 0; j < 4; ++j) {
        m[j] = fmaxf(fmaxf(fmaxf(g0[j].x + b0.x, g0[j].y + b0.y),
                           fmaxf(g0[j].z + b0.z, g0[j].w + b0.w)),
                     fmaxf(fmaxf(g1[j].x + b1.x, g1[j].y + b1.y),
                           fmaxf(g1[j].z + b1.z, g1[j].w + b1.w)));
    }

    #pragma unroll
    for (int off = 32; off > 0; off >>= 1) {
        #pragma unroll
        for (int j = 0; j < 4; ++j)
            m[j] = fmaxf(m[j], __shfl_down(m[j], off, 64));
    }

    if (lane == 0) {
        s_add[kbase + 0] = m[0];
        s_add[kbase + 1] = m[1];
        s_add[kbase + 2] = m[2];
        s_add[kbase + 3] = m[3];
    }
    __syncthreads();

    if (threadIdx.x == 0) {
        float sum = 0.0f;
        #pragma unroll
        for (int i = 0; i < 16; ++i) sum += s_add[i];
        out[3 + b] = fmaxf(0.5f, (2.0f - sum * (1.0f / 16.0f)) * 0.5f);
        wpart[b] = weights[b] * sum;
    }
}

// ---------------------------------------------------------------------------
// Kernel 2: per-column partial sums. 256 blocks x 512 threads (thread = bin),
// each block sums a contiguous chunk of rows. Plain stores.
// ---------------------------------------------------------------------------
__global__ __launch_bounds__(NBINS) void colsum_kernel(
        const float* __restrict__ outputs,
        float* __restrict__ part,       // (nblocks * NBINS) in ws
        int rows_per_block) {
    const int t = threadIdx.x;
    const size_t r0 = (size_t)blockIdx.x * rows_per_block;
    float local = 0.0f;
    for (int r = 0; r < rows_per_block; ++r)
        local += outputs[(r0 + r) * NBINS + t];
    part[(size_t)blockIdx.x * NBINS + t] = local;
}

// ---------------------------------------------------------------------------
// Kernel 3: finalize. 512 threads: (a) sum column partials -> min/max reduce;
// (b) parallel-reduce wpart (B values); thread 0 writes the 3 scalars.
// ---------------------------------------------------------------------------
__global__ __launch_bounds__(NBINS) void final_kernel(
        const float* __restrict__ part,
        const float* __restrict__ wpart,
        float* __restrict__ out,
        int npart, int B, float inv_count, float inv_target) {
    __shared__ float smax[NBINS];
    __shared__ float smin[NBINS];
    __shared__ float ssum[NBINS];
    const int t = threadIdx.x;

    float v = 0.0f;
    for (int j = 0; j < npart; ++j)
        v += part[(size_t)j * NBINS + t];
    smax[t] = v;
    smin[t] = v;

    float ws = 0.0f;
    for (int i = t; i < B; i += NBINS)
        ws += wpart[i];
    ssum[t] = ws;
    __syncthreads();

    for (int s = NBINS / 2; s > 0; s >>= 1) {
        if (t < s) {
            smax[t] = fmaxf(smax[t], smax[t + s]);
            smin[t] = fminf(smin[t], smin[t + s]);
            ssum[t] += ssum[t + s];
        }
        __syncthreads();
    }
    if (t == 0) {
        float add_mean = ssum[0] * inv_count;
        float d = 2.0f - add_mean;
        float diff = d * d;
        float bn = (smax[0] - smin[0]) * inv_target;
        out[0] = bn + diff;
        out[1] = diff;
        out[2] = bn;
    }
}

extern "C" void kernel_launch(void* const* d_in, const int* in_sizes, int n_in,
                              void* d_out, int out_size, void* d_ws, size_t ws_size,
                              hipStream_t stream) {
    const float* outputs = (const float*)d_in[0];  // (N, 512)
    const float* y       = (const float*)d_in[1];  // (B, K)
    const float* weights = (const float*)d_in[2];  // (B,)
    float* out = (float*)d_out;

    const int B = in_sizes[2];              // 8192
    const int K = in_sizes[1] / B;          // 16
    const int N = in_sizes[0] / NBINS;      // 100000

    const int COL_BLOCKS = 256;
    const int rows_per_block = B / COL_BLOCKS;   // 32

    // ws layout (floats): wpart[B] | colpart[COL_BLOCKS*NBINS]
    float* ws      = (float*)d_ws;
    float* wpart   = ws;
    float* colpart = wpart + B;

    gather_kernel<<<B, BDIM, 0, stream>>>(outputs, y, weights, out, wpart, K);
    colsum_kernel<<<COL_BLOCKS, NBINS, 0, stream>>>(outputs, colpart, rows_per_block);
    final_kernel<<<1, NBINS, 0, stream>>>(colpart, wpart, out,
                                          COL_BLOCKS, B,
                                          1.0f / (float)(B * K),
                                          (float)NBINS / (float)N);
}